// Round 3
// baseline (130.590 us; speedup 1.0000x reference)
//
#include <hip/hip_runtime.h>
#include <math.h>

#define E_DIM 512
#define H_DIM 8
#define WIN 128
#define L_SEQ 4096
#define B_SZ 2

typedef unsigned short ushort_t;
typedef unsigned int uint_t;
typedef __attribute__((ext_vector_type(8))) __bf16 bf16x8;
typedef __attribute__((ext_vector_type(4))) float f32x4;

// ---------- bf16 helpers ----------
__device__ __forceinline__ ushort_t f2bf(float f) {
    uint_t u = __float_as_uint(f);
    u = u + 0x7fffu + ((u >> 16) & 1u);
    return (ushort_t)(u >> 16);
}
// packed f32x2 -> bf16x2 (RNE), single instruction
__device__ __forceinline__ uint_t pk2bf(float lo, float hi) {
    uint_t r;
    asm("v_cvt_pk_bf16_f32 %0, %1, %2" : "=v"(r) : "v"(lo), "v"(hi));
    return r;
}

__device__ __forceinline__ void gload16(const ushort_t* g, ushort_t* l) {
    __builtin_amdgcn_global_load_lds(
        (const __attribute__((address_space(1))) void*)g,
        (__attribute__((address_space(3))) void*)l,
        16, 0, 0);
}

// ===== Tile image (16 rows x 32 k = 512 elems = 1 KB) =====
// idx = slot*8 + (k&7), slot = ((k>>3)&3)*16 + (row&15)  [slot = quad*16+ln]
// A-frag & B-frag both read at lane*8 within a tile image.

// ---------- convert: x, w1, w2 -> hi-only tiled bf16 ----------
__global__ __launch_bounds__(256) void convertX(
    const float* __restrict__ x,  ushort_t* __restrict__ xh,
    const float* __restrict__ w1, ushort_t* __restrict__ w1h,
    const float* __restrict__ w2, ushort_t* __restrict__ w2h) {
    int sg = blockIdx.x * 256 + threadIdx.x;
    const float* src; ushort_t* dh;
    if (sg < 524288)      { src = x;  dh = xh; }
    else if (sg < 622592) { src = w1; dh = w1h; sg -= 524288; }
    else                  { src = w2; dh = w2h; sg -= 622592; }
    const int tile = sg >> 6, slot = sg & 63;
    const int row = (tile >> 4) * 16 + (slot & 15);
    const int k   = (tile & 15) * 32 + (slot >> 4) * 8;
    const float4 v0 = *(const float4*)&src[(size_t)row * 512 + k];
    const float4 v1 = *(const float4*)&src[(size_t)row * 512 + k + 4];
    uint4 ov;
    ov.x = pk2bf(v0.x, v0.y);
    ov.y = pk2bf(v0.z, v0.w);
    ov.z = pk2bf(v1.x, v1.y);
    ov.w = pk2bf(v1.z, v1.w);
    *(uint4*)(dh + (size_t)sg * 8) = ov;
}

// ---------- GEMM1: qkv projection, 1-term (hi x hi), BK=32, 2-deep dbuf ----
// 128x128 tile, grid (64, 12). by<4: q, [4,8): k, >=8: v. All outputs hi-only.
__global__ __launch_bounds__(256) void gemm_qkv(
    const ushort_t* __restrict__ Ah,
    const ushort_t* __restrict__ Wh,
    const float* __restrict__ bias,
    ushort_t* __restrict__ qTh,
    ushort_t* __restrict__ kTh,
    ushort_t* __restrict__ vTh) {
    __shared__ __align__(16) ushort_t sAh[2][8 * 512];
    __shared__ __align__(16) ushort_t sWh[2][8 * 512];

    const int tid = threadIdx.x, lane = tid & 63, w = tid >> 6;
    const int wm = w & 1, wn = w >> 1, ln = lane & 15, quad = lane >> 4;
    const int bx = blockIdx.x, by = blockIdx.y;
    const int lo8 = lane * 8;
    const int wu = __builtin_amdgcn_readfirstlane(w);

    f32x4 acc[4][4];
    const f32x4 zero = {0.f, 0.f, 0.f, 0.f};
    #pragma unroll
    for (int i = 0; i < 4; i++)
        #pragma unroll
        for (int j = 0; j < 4; j++) acc[i][j] = zero;

    // staging: 16 images per k-group (A 8, Wh 8), 4 per wave
    const ushort_t* pb[4];
    ushort_t* db0[4];
    ushort_t* db1[4];
    #pragma unroll
    for (int t = 0; t < 4; t++) {
        const int g = wu * 4 + t;
        if (g < 8) {
            pb[t] = Ah + ((size_t)(bx * 8 + g) * 16) * 512;
            db0[t] = &sAh[0][g * 512]; db1[t] = &sAh[1][g * 512];
        } else {
            const int u = g - 8;
            pb[t] = Wh + ((size_t)(by * 8 + u) * 16) * 512;
            db0[t] = &sWh[0][u * 512]; db1[t] = &sWh[1][u * 512];
        }
    }

    // prologue: stage k-group 0 into buf 0
    #pragma unroll
    for (int t = 0; t < 4; t++)
        gload16(pb[t] + lo8, db0[t]);

    for (int kt = 0; kt < 16; kt++) {
        __syncthreads();
        if (kt < 15) {
            const int koff = (kt + 1) * 512;
            if ((kt + 1) & 1) {
                #pragma unroll
                for (int t = 0; t < 4; t++) gload16(pb[t] + koff + lo8, db1[t]);
            } else {
                #pragma unroll
                for (int t = 0; t < 4; t++) gload16(pb[t] + koff + lo8, db0[t]);
            }
        }
        const int cb = kt & 1;
        bf16x8 fah[4];
        #pragma unroll
        for (int i = 0; i < 4; i++)
            fah[i] = *(const bf16x8*)&sAh[cb][(wm * 4 + i) * 512 + lo8];
        #pragma unroll
        for (int j = 0; j < 4; j++) {
            const bf16x8 fbh = *(const bf16x8*)&sWh[cb][(wn * 4 + j) * 512 + lo8];
            #pragma unroll
            for (int i = 0; i < 4; i++)
                acc[i][j] = __builtin_amdgcn_mfma_f32_16x16x32_bf16(fah[i], fbh, acc[i][j], 0, 0, 0);
        }
    }

    // ---- epilogue: C/D layout col=ln (within j-tile), row=quad*4+r ----
    const int b = bx >> 5;
    const int h = 2 * (by & 3) + wn;
    if (by < 8) {
        ushort_t* dh = (by < 4) ? qTh : kTh;
        #pragma unroll
        for (int i = 0; i < 4; i++) {
            const int rt = (bx & 31) * 8 + wm * 4 + i;
            const size_t tb = ((size_t)(b * 8 + h) * 256 + rt) * 2;
            #pragma unroll
            for (int j = 0; j < 4; j++) {
                const float bv = bias[by * 128 + wn * 64 + j * 16 + ln];
                const size_t tile = tb + (j >> 1);
                const uint_t pa = pk2bf(acc[i][j][0] + bv, acc[i][j][1] + bv);
                const uint_t pc = pk2bf(acc[i][j][2] + bv, acc[i][j][3] + bv);
                const int slot0 = ((j * 2 + (ln >> 3)) & 3) * 16 + quad * 4;
                const size_t idx0 = tile * 512 + slot0 * 8 + (ln & 7);
                dh[idx0]      = (ushort_t)pa;
                dh[idx0 + 8]  = (ushort_t)(pa >> 16);
                dh[idx0 + 16] = (ushort_t)pc;
                dh[idx0 + 24] = (ushort_t)(pc >> 16);
            }
        }
    } else {
        const int kwin = (bx & 31) * 2 + wm;
        #pragma unroll
        for (int i = 0; i < 4; i++) {
            const int kk = i >> 1;
            #pragma unroll
            for (int j = 0; j < 4; j++) {
                const float bv = bias[by * 128 + wn * 64 + j * 16 + ln];
                const size_t tile = (((size_t)(b * 8 + h) * 64 + kwin) * 4 + j) * 2 + kk;
                // klq = quad*4+r: klq>>3 == quad>>1 (r-invariant) -> 4 consecutive elems
                const uint_t pa = pk2bf(acc[i][j][0] + bv, acc[i][j][1] + bv);
                const uint_t pc = pk2bf(acc[i][j][2] + bv, acc[i][j][3] + bv);
                const int slot = ((i & 1) * 2 + (quad >> 1)) * 16 + ln;
                uint2 ov; ov.x = pa; ov.y = pc;
                *(uint2*)&vTh[tile * 512 + slot * 8 + (quad & 1) * 4] = ov;
            }
        }
    }
}

// ---------- attention: 128-q blocks, 8 waves, swapped QK^T, scalar softmax --
// S^T = mfma(K,Q): lane (ln,quad) holds S[q=qlo+ln][k=ks+jt*16+quad*4+r].
// Softmax state (m,l) is a per-lane SCALAR (one q-row per lane, ln).
// Max taken over the UNMASKED superset (valid: any m >= true max; p<=1 always);
// mask applied as cndmask-to-zero after exp2.
__global__ __launch_bounds__(512) void attn_mfma(
    const ushort_t* __restrict__ qTh,
    const ushort_t* __restrict__ kTh,
    const ushort_t* __restrict__ vTh,
    ushort_t* __restrict__ outh) {
    __shared__ __align__(16) ushort_t sKh[2][8 * 512];
    __shared__ __align__(16) ushort_t sV [2][8 * 512];
    __shared__ __align__(16) ushort_t sP [16 * 512];

    const int qs = blockIdx.x * 128;
    const int h = blockIdx.y, b = blockIdx.z;
    const int bh = b * 8 + h;
    const int tid = threadIdx.x, lane = tid & 63;
    const int w = tid >> 6, ln = lane & 15, quad = lane >> 4;
    const int lo8 = lane * 8;

    // Q fragments (hi only)
    bf16x8 qf[2];
    {
        const size_t qt = ((size_t)bh * 256 + (qs >> 4) + w) * 2;
        qf[0] = *(const bf16x8*)(qTh + (qt + 0) * 512 + lo8);
        qf[1] = *(const bf16x8*)(qTh + (qt + 1) * 512 + lo8);
    }

    f32x4 oacc[4];
    const f32x4 zero = {0.f, 0.f, 0.f, 0.f};
    #pragma unroll
    for (int dt = 0; dt < 4; dt++) oacc[dt] = zero;
    float m_run = -1e30f, l_run = 0.f;

    const float cscale = 0.125f * 1.44269504f;
    const int qlo = qs + 16 * w;
    const int q = qlo + ln;  // this lane's softmax q-row
    const int lo_b = (q - WIN) < 0 ? 0 : (q - WIN);
    const int hi_b = (q + WIN) > (L_SEQ - 1) ? (L_SEQ - 1) : (q + WIN);

    // prologue: kt = 0 into buf 0
    {
        if (w < 4) {
            int st = (qs >> 4) - 8 + w;
            st = st < 0 ? 0 : (st > 255 ? 255 : st);
            const size_t kb = ((size_t)bh * 256 + st) * 2 * 512 + lo8;
            gload16(kTh + kb,       &sKh[0][(w * 2 + 0) * 512]);
            gload16(kTh + kb + 512, &sKh[0][(w * 2 + 1) * 512]);
        } else {
            const int u = w - 4;
            int vw = (qs >> 6) - 2;
            vw = vw < 0 ? 0 : (vw > 63 ? 63 : vw);
            const size_t vb = (((size_t)bh * 64 + vw) * 4 + u) * 2 * 512 + lo8;
            gload16(vTh + vb,       &sV[0][(u * 2 + 0) * 512]);
            gload16(vTh + vb + 512, &sV[0][(u * 2 + 1) * 512]);
        }
    }

    for (int kt = 0; kt < 6; kt++) {
        const int ks = qs - 128 + kt * 64;

        __syncthreads();  // drains stage(kt); all waves done reading buf[(kt+1)&1]

        if (kt < 5) {
            const int nb = (kt + 1) & 1;
            if (w < 4) {
                int st = (qs >> 4) - 8 + (kt + 1) * 4 + w;
                st = st < 0 ? 0 : (st > 255 ? 255 : st);
                const size_t kb = ((size_t)bh * 256 + st) * 2 * 512 + lo8;
                gload16(kTh + kb,       &sKh[nb][(w * 2 + 0) * 512]);
                gload16(kTh + kb + 512, &sKh[nb][(w * 2 + 1) * 512]);
            } else {
                const int u = w - 4;
                int vw = (qs >> 6) - 2 + kt + 1;
                vw = vw < 0 ? 0 : (vw > 63 ? 63 : vw);
                const size_t vb = (((size_t)bh * 64 + vw) * 4 + u) * 2 * 512 + lo8;
                gload16(vTh + vb,       &sV[nb][(u * 2 + 0) * 512]);
                gload16(vTh + vb + 512, &sV[nb][(u * 2 + 1) * 512]);
            }
        }
        const int cb = kt & 1;

        // per-jt dead flags (wave-uniform)
        bool dead[4];
        #pragma unroll
        for (int jt = 0; jt < 4; jt++) {
            const int klo = ks + 16 * jt;
            dead[jt] = (klo > qlo + 15 + WIN) || (klo + 15 < qlo - WIN) ||
                       (klo >= L_SEQ) || (klo + 15 < 0);
        }
        const bool hdead0 = dead[0] && dead[1];
        const bool hdead1 = dead[2] && dead[3];
        const bool ktAlive = !(hdead0 && hdead1);

        if (ktAlive) {
            // S^T = K Q^T (swapped operands)
            f32x4 st4[4];
            __builtin_amdgcn_s_setprio(1);
            #pragma unroll
            for (int jt = 0; jt < 4; jt++) {
                f32x4 a = zero;
                if (!dead[jt]) {
                    #pragma unroll
                    for (int kk = 0; kk < 2; kk++) {
                        const bf16x8 kh = *(const bf16x8*)&sKh[cb][(jt * 2 + kk) * 512 + lo8];
                        a = __builtin_amdgcn_mfma_f32_16x16x32_bf16(kh, qf[kk], a, 0, 0, 0);
                    }
                }
                st4[jt] = a;
            }
            __builtin_amdgcn_s_setprio(0);

            // unmasked row max (raw S), then scale once
            float mkr = -INFINITY;
            #pragma unroll
            for (int jt = 0; jt < 4; jt++)
                if (!dead[jt])
                    #pragma unroll
                    for (int r = 0; r < 4; r++)
                        mkr = fmaxf(mkr, st4[jt][r]);
            mkr = fmaxf(mkr, __shfl_xor(mkr, 16));
            mkr = fmaxf(mkr, __shfl_xor(mkr, 32));

            const float mnew = fmaxf(m_run, mkr * cscale);
            const bool raised = mnew > m_run;
            const float alpha = exp2f(m_run - mnew);
            m_run = mnew;

            // p = exp2(fma(S, cscale, -mnew)), masked to 0
            float ps = 0.f;
            #pragma unroll
            for (int jt = 0; jt < 4; jt++) {
                if (!dead[jt]) {
                    #pragma unroll
                    for (int r = 0; r < 4; r++) {
                        const int kcol = ks + jt * 16 + quad * 4 + r;
                        const bool ok = (kcol >= lo_b) && (kcol <= hi_b) && (kcol != q);
                        float p = exp2f(st4[jt][r] * cscale - mnew);
                        p = ok ? p : 0.f;
                        st4[jt][r] = p;
                        ps += p;
                    }
                }
            }
            ps += __shfl_xor(ps, 16);
            ps += __shfl_xor(ps, 32);
            l_run = l_run * alpha + ps;

            // rescale O only if some lane raised its max
            if (__any(raised)) {
                float ar[4];
                #pragma unroll
                for (int r = 0; r < 4; r++)
                    ar[r] = __shfl(alpha, quad * 4 + r);
                #pragma unroll
                for (int dt = 0; dt < 4; dt++)
                    #pragma unroll
                    for (int r = 0; r < 4; r++)
                        oacc[dt][r] *= ar[r];
            }

            // P -> sP image (row = q&15 = ln, k = key-in-window), uint2 writes
            #pragma unroll
            for (int jt = 0; jt < 4; jt++) {
                const bool hd = (jt < 2) ? hdead0 : hdead1;
                if (!hd) {
                    uint2 pw;
                    if (!dead[jt]) {
                        pw.x = pk2bf(st4[jt][0], st4[jt][1]);
                        pw.y = pk2bf(st4[jt][2], st4[jt][3]);
                    } else { pw.x = 0u; pw.y = 0u; }
                    const int slot = ((jt & 1) * 2 + (quad >> 1)) * 16 + ln;
                    *(uint2*)&sP[w * 1024 + (jt >> 1) * 512 + slot * 8 + (quad & 1) * 4] = pw;
                }
            }

            // O += P V (original operand order; pf as A from image); skip dead halves
            #pragma unroll
            for (int kk = 0; kk < 2; kk++) {
                const bool hd = (kk == 0) ? hdead0 : hdead1;
                if (!hd) {
                    const bf16x8 pf = *(const bf16x8*)&sP[w * 1024 + kk * 512 + lo8];
                    __builtin_amdgcn_s_setprio(1);
                    #pragma unroll
                    for (int dt = 0; dt < 4; dt++) {
                        const bf16x8 vf = *(const bf16x8*)&sV[cb][(dt * 2 + kk) * 512 + lo8];
                        oacc[dt] = __builtin_amdgcn_mfma_f32_16x16x32_bf16(pf, vf, oacc[dt], 0, 0, 0);
                    }
                    __builtin_amdgcn_s_setprio(0);
                }
            }
        }
    }

    // epilogue: lane holds O[q=qlo+quad*4+r][d=dt*16+ln];
    // l for row quad*4+r is broadcast from lane (quad*4+r).
    const int Rt = ((b * L_SEQ + qs) >> 4) + w;
    float invl[4];
    #pragma unroll
    for (int r = 0; r < 4; r++) {
        const float lr = __shfl(l_run, quad * 4 + r);
        invl[r] = __builtin_amdgcn_rcpf(lr);
    }
    #pragma unroll
    for (int dt = 0; dt < 4; dt++) {
        const uint_t pa = pk2bf(oacc[dt][0] * invl[0], oacc[dt][1] * invl[1]);
        const uint_t pc = pk2bf(oacc[dt][2] * invl[2], oacc[dt][3] * invl[3]);
        const int tile = Rt * 16 + h * 2 + (dt >> 1);
        const int slot0 = ((dt & 1) * 2 + (ln >> 3)) * 16 + quad * 4;
        const size_t idx0 = (size_t)tile * 512 + slot0 * 8 + (ln & 7);
        outh[idx0]      = (ushort_t)pa;
        outh[idx0 + 8]  = (ushort_t)(pa >> 16);
        outh[idx0 + 16] = (ushort_t)pc;
        outh[idx0 + 24] = (ushort_t)(pc >> 16);
    }
}

// ---------- GEMM2: out projection, 128x64, 8 waves, BK=64, 1-term, dbuf -----
__global__ __launch_bounds__(512) void gemm_out(
    const ushort_t* __restrict__ Ah,
    const ushort_t* __restrict__ Wh,
    const float* __restrict__ bias, float* __restrict__ C) {
    __shared__ __align__(16) ushort_t sAh[2][16 * 512];
    __shared__ __align__(16) ushort_t sWh[2][8 * 512];

    const int tid = threadIdx.x, lane = tid & 63, w = tid >> 6;
    const int wm = w & 3, wn = w >> 2, ln = lane & 15, quad = lane >> 4;
    const int bx = blockIdx.x, by = blockIdx.y;
    const int lo8 = lane * 8;
    const int wu = __builtin_amdgcn_readfirstlane(w);

    f32x4 acc[2][2];
    const f32x4 zero = {0.f, 0.f, 0.f, 0.f};
    #pragma unroll
    for (int i = 0; i < 2; i++)
        #pragma unroll
        for (int j = 0; j < 2; j++) acc[i][j] = zero;

    const ushort_t* pb[3];
    ushort_t* db0[3];
    ushort_t* db1[3];
    #pragma unroll
    for (int t = 0; t < 3; t++) {
        const int g = wu * 3 + t;
        if (g < 16) {
            pb[t] = Ah + ((size_t)(bx * 8 + (g >> 1)) * 16 + (g & 1)) * 512;
            db0[t] = &sAh[0][g * 512]; db1[t] = &sAh[1][g * 512];
        } else {
            const int u = g - 16;
            pb[t] = Wh + ((size_t)(by * 4 + (u >> 1)) * 16 + (u & 1)) * 512;
            db0[t] = &sWh[0][u * 512]; db1[t] = &sWh[1][u * 512];
        }
    }

    #pragma unroll
    for (int t = 0; t < 3; t++)
        gload16(pb[t] + lo8, db0[t]);

    for (int KT = 0; KT < 8; KT++) {
        __syncthreads();
        if (KT < 7) {
            const int koff = (KT + 1) * 1024;
            if ((KT + 1) & 1) {
                #pragma unroll
                for (int t = 0; t < 3; t++) gload16(pb[t] + koff + lo8, db1[t]);
            } else {
                #pragma unroll
                for (int t = 0; t < 3; t++) gload16(pb[t] + koff + lo8, db0[t]);
            }
        }
        const int cb = KT & 1;
        #pragma unroll
        for (int ks = 0; ks < 2; ks++) {
            bf16x8 fah[2];
            #pragma unroll
            for (int i = 0; i < 2; i++)
                fah[i] = *(const bf16x8*)&sAh[cb][((wm * 2 + i) * 2 + ks) * 512 + lo8];
            #pragma unroll
            for (int j = 0; j < 2; j++) {
                const bf16x8 fbh = *(const bf16x8*)&sWh[cb][((wn * 2 + j) * 2 + ks) * 512 + lo8];
                #pragma unroll
                for (int i = 0; i < 2; i++)
                    acc[i][j] = __builtin_amdgcn_mfma_f32_16x16x32_bf16(fah[i], fbh, acc[i][j], 0, 0, 0);
            }
        }
    }

    #pragma unroll
    for (int i = 0; i < 2; i++) {
        const int row0 = bx * 128 + wm * 32 + i * 16 + quad * 4;
        #pragma unroll
        for (int j = 0; j < 2; j++) {
            const int col = by * 64 + wn * 32 + j * 16 + ln;
            const float bv = bias[col];
            #pragma unroll
            for (int r = 0; r < 4; r++)
                C[(size_t)(row0 + r) * E_DIM + col] = acc[i][j][r] + bv;
        }
    }
}

extern "C" void kernel_launch(void* const* d_in, const int* in_sizes, int n_in,
                              void* d_out, int out_size, void* d_ws, size_t ws_size,
                              hipStream_t stream) {
    const float* x         = (const float*)d_in[0];
    const float* in_proj_w = (const float*)d_in[1];
    const float* in_proj_b = (const float*)d_in[2];
    const float* out_w     = (const float*)d_in[3];
    const float* out_b     = (const float*)d_in[4];
    float* out = (float*)d_out;

    const int N = B_SZ * L_SEQ;  // 8192
    const size_t NE = (size_t)N * E_DIM;  // 4.19M elems

    char* p = (char*)d_ws;
    ushort_t* xh  = (ushort_t*)p; p += NE * 2;
    ushort_t* w1h = (ushort_t*)p; p += (size_t)3 * E_DIM * E_DIM * 2;
    ushort_t* w2h = (ushort_t*)p; p += (size_t)E_DIM * E_DIM * 2;
    ushort_t* qTh = (ushort_t*)p; p += NE * 2;
    ushort_t* kTh = (ushort_t*)p; p += NE * 2;
    ushort_t* vTh = (ushort_t*)p; p += NE * 2;
    ushort_t* ath = (ushort_t*)p; p += NE * 2;
    // total ~46 MB

    convertX<<<2560, 256, 0, stream>>>(x, xh, in_proj_w, w1h, out_w, w2h);

    gemm_qkv<<<dim3(64, 12), 256, 0, stream>>>(
        xh, w1h, in_proj_b, qTh, kTh, vTh);

    attn_mfma<<<dim3(L_SEQ / 128, H_DIM, B_SZ), 512, 0, stream>>>(
        qTh, kTh, vTh, ath);

    gemm_out<<<dim3(64, 8), 512, 0, stream>>>(
        ath, w2h, out_b, out);
}

// Round 4
// 127.071 us; speedup vs baseline: 1.0277x; 1.0277x over previous
//
#include <hip/hip_runtime.h>
#include <math.h>

#define E_DIM 512
#define H_DIM 8
#define WIN 128
#define L_SEQ 4096
#define B_SZ 2

typedef unsigned short ushort_t;
typedef unsigned int uint_t;
typedef __attribute__((ext_vector_type(8))) __bf16 bf16x8;
typedef __attribute__((ext_vector_type(4))) float f32x4;

// ---------- bf16 helpers ----------
__device__ __forceinline__ ushort_t f2bf(float f) {
    uint_t u = __float_as_uint(f);
    u = u + 0x7fffu + ((u >> 16) & 1u);
    return (ushort_t)(u >> 16);
}
// packed f32x2 -> bf16x2 (RNE), single instruction
__device__ __forceinline__ uint_t pk2bf(float lo, float hi) {
    uint_t r;
    asm("v_cvt_pk_bf16_f32 %0, %1, %2" : "=v"(r) : "v"(lo), "v"(hi));
    return r;
}

__device__ __forceinline__ void gload16(const ushort_t* g, ushort_t* l) {
    __builtin_amdgcn_global_load_lds(
        (const __attribute__((address_space(1))) void*)g,
        (__attribute__((address_space(3))) void*)l,
        16, 0, 0);
}

// ===== Tile image (16 rows x 32 k = 512 elems = 1 KB) =====
// idx = slot*8 + (k&7), slot = ((k>>3)&3)*16 + (row&15)  [slot = quad*16+ln]
// A-frag & B-frag both read at lane*8 within a tile image.

// ---------- convert: x, w1, w2 -> hi-only tiled bf16 ----------
__global__ __launch_bounds__(256) void convertX(
    const float* __restrict__ x,  ushort_t* __restrict__ xh,
    const float* __restrict__ w1, ushort_t* __restrict__ w1h,
    const float* __restrict__ w2, ushort_t* __restrict__ w2h) {
    int sg = blockIdx.x * 256 + threadIdx.x;
    const float* src; ushort_t* dh;
    if (sg < 524288)      { src = x;  dh = xh; }
    else if (sg < 622592) { src = w1; dh = w1h; sg -= 524288; }
    else                  { src = w2; dh = w2h; sg -= 622592; }
    const int tile = sg >> 6, slot = sg & 63;
    const int row = (tile >> 4) * 16 + (slot & 15);
    const int k   = (tile & 15) * 32 + (slot >> 4) * 8;
    const float4 v0 = *(const float4*)&src[(size_t)row * 512 + k];
    const float4 v1 = *(const float4*)&src[(size_t)row * 512 + k + 4];
    uint4 ov;
    ov.x = pk2bf(v0.x, v0.y);
    ov.y = pk2bf(v0.z, v0.w);
    ov.z = pk2bf(v1.x, v1.y);
    ov.w = pk2bf(v1.z, v1.w);
    *(uint4*)(dh + (size_t)sg * 8) = ov;
}

// ---------- GEMM1: qkv projection, BK=32, TRIPLE buffer, counted vmcnt ----
// 128x128 tile, grid (64, 12). by<4: q, [4,8): k, >=8: v. All outputs hi-only.
// Per iter: wait own loads(kt) (vmcnt<=4 keeps loads(kt+1) in flight),
// lgkmcnt(0) (my prev-buffer ds_reads done), s_barrier, stage(kt+2), compute.
__global__ __launch_bounds__(256) void gemm_qkv(
    const ushort_t* __restrict__ Ah,
    const ushort_t* __restrict__ Wh,
    const float* __restrict__ bias,
    ushort_t* __restrict__ qTh,
    ushort_t* __restrict__ kTh,
    ushort_t* __restrict__ vTh) {
    __shared__ __align__(16) ushort_t sAh[3][8 * 512];
    __shared__ __align__(16) ushort_t sWh[3][8 * 512];

    const int tid = threadIdx.x, lane = tid & 63, w = tid >> 6;
    const int wm = w & 1, wn = w >> 1, ln = lane & 15, quad = lane >> 4;
    const int bx = blockIdx.x, by = blockIdx.y;
    const int lo8 = lane * 8;
    const int wu = __builtin_amdgcn_readfirstlane(w);

    const ushort_t* sA0 = &sAh[0][0];
    const ushort_t* sW0 = &sWh[0][0];
    const int BUF = 8 * 512;  // elems per buffer (both arrays)

    f32x4 acc[4][4];
    const f32x4 zero = {0.f, 0.f, 0.f, 0.f};
    #pragma unroll
    for (int i = 0; i < 4; i++)
        #pragma unroll
        for (int j = 0; j < 4; j++) acc[i][j] = zero;

    // staging: 16 images per k-group (A 8, Wh 8), 4 per wave
    const ushort_t* pb[4];
    ushort_t* db[4];  // dst in buffer 0
    #pragma unroll
    for (int t = 0; t < 4; t++) {
        const int g = wu * 4 + t;
        if (g < 8) {
            pb[t] = Ah + ((size_t)(bx * 8 + g) * 16) * 512;
            db[t] = &sAh[0][g * 512];
        } else {
            const int u = g - 8;
            pb[t] = Wh + ((size_t)(by * 8 + u) * 16) * 512;
            db[t] = &sWh[0][u * 512];
        }
    }

    // prologue: stage kt=0 -> buf0, kt=1 -> buf1 (8 loads in FIFO order)
    #pragma unroll
    for (int t = 0; t < 4; t++) gload16(pb[t] + lo8, db[t]);
    #pragma unroll
    for (int t = 0; t < 4; t++) gload16(pb[t] + 512 + lo8, db[t] + BUF);

    int bw = 2, br = 0;
    for (int kt = 0; kt < 16; kt++) {
        if (kt < 15) asm volatile("s_waitcnt vmcnt(4) lgkmcnt(0)" ::: "memory");
        else         asm volatile("s_waitcnt vmcnt(0) lgkmcnt(0)" ::: "memory");
        __builtin_amdgcn_s_barrier();
        __builtin_amdgcn_sched_barrier(0);

        if (kt < 14) {
            const int koff = (kt + 2) * 512;
            const int bwo = bw * BUF;
            #pragma unroll
            for (int t = 0; t < 4; t++)
                gload16(pb[t] + koff + lo8, db[t] + bwo);
            bw = (bw == 2) ? 0 : bw + 1;
        }

        const int bro = br * BUF;
        br = (br == 2) ? 0 : br + 1;

        bf16x8 fah[4];
        #pragma unroll
        for (int i = 0; i < 4; i++)
            fah[i] = *(const bf16x8*)&sA0[bro + (wm * 4 + i) * 512 + lo8];
        #pragma unroll
        for (int j = 0; j < 4; j++) {
            const bf16x8 fbh = *(const bf16x8*)&sW0[bro + (wn * 4 + j) * 512 + lo8];
            #pragma unroll
            for (int i = 0; i < 4; i++)
                acc[i][j] = __builtin_amdgcn_mfma_f32_16x16x32_bf16(fah[i], fbh, acc[i][j], 0, 0, 0);
        }
    }

    // ---- epilogue: C/D layout col=ln (within j-tile), row=quad*4+r ----
    const int b = bx >> 5;
    const int h = 2 * (by & 3) + wn;
    if (by < 8) {
        ushort_t* dh = (by < 4) ? qTh : kTh;
        #pragma unroll
        for (int i = 0; i < 4; i++) {
            const int rt = (bx & 31) * 8 + wm * 4 + i;
            const size_t tb = ((size_t)(b * 8 + h) * 256 + rt) * 2;
            #pragma unroll
            for (int j = 0; j < 4; j++) {
                const float bv = bias[by * 128 + wn * 64 + j * 16 + ln];
                const size_t tile = tb + (j >> 1);
                const uint_t pa = pk2bf(acc[i][j][0] + bv, acc[i][j][1] + bv);
                const uint_t pc = pk2bf(acc[i][j][2] + bv, acc[i][j][3] + bv);
                const int slot0 = ((j * 2 + (ln >> 3)) & 3) * 16 + quad * 4;
                const size_t idx0 = tile * 512 + slot0 * 8 + (ln & 7);
                dh[idx0]      = (ushort_t)pa;
                dh[idx0 + 8]  = (ushort_t)(pa >> 16);
                dh[idx0 + 16] = (ushort_t)pc;
                dh[idx0 + 24] = (ushort_t)(pc >> 16);
            }
        }
    } else {
        const int kwin = (bx & 31) * 2 + wm;
        #pragma unroll
        for (int i = 0; i < 4; i++) {
            const int kk = i >> 1;
            #pragma unroll
            for (int j = 0; j < 4; j++) {
                const float bv = bias[by * 128 + wn * 64 + j * 16 + ln];
                const size_t tile = (((size_t)(b * 8 + h) * 64 + kwin) * 4 + j) * 2 + kk;
                // klq = quad*4+r: klq>>3 == quad>>1 (r-invariant) -> 4 consecutive elems
                const uint_t pa = pk2bf(acc[i][j][0] + bv, acc[i][j][1] + bv);
                const uint_t pc = pk2bf(acc[i][j][2] + bv, acc[i][j][3] + bv);
                const int slot = ((i & 1) * 2 + (quad >> 1)) * 16 + ln;
                uint2 ov; ov.x = pa; ov.y = pc;
                *(uint2*)&vTh[tile * 512 + slot * 8 + (quad & 1) * 4] = ov;
            }
        }
    }
}

// ---------- attention: 128-q blocks, 8 waves, swapped QK^T, scalar softmax --
// S^T = mfma(K,Q): lane (ln,quad) holds S[q=qlo+ln][k=ks+jt*16+quad*4+r].
// Softmax state (m,l) is a per-lane SCALAR (one q-row per lane, ln).
// Max taken over the UNMASKED superset (valid: any m >= true max; p<=1 always);
// mask applied as cndmask-to-zero after exp2.
__global__ __launch_bounds__(512) void attn_mfma(
    const ushort_t* __restrict__ qTh,
    const ushort_t* __restrict__ kTh,
    const ushort_t* __restrict__ vTh,
    ushort_t* __restrict__ outh) {
    __shared__ __align__(16) ushort_t sKh[2][8 * 512];
    __shared__ __align__(16) ushort_t sV [2][8 * 512];
    __shared__ __align__(16) ushort_t sP [16 * 512];

    const int qs = blockIdx.x * 128;
    const int h = blockIdx.y, b = blockIdx.z;
    const int bh = b * 8 + h;
    const int tid = threadIdx.x, lane = tid & 63;
    const int w = tid >> 6, ln = lane & 15, quad = lane >> 4;
    const int lo8 = lane * 8;

    // Q fragments (hi only)
    bf16x8 qf[2];
    {
        const size_t qt = ((size_t)bh * 256 + (qs >> 4) + w) * 2;
        qf[0] = *(const bf16x8*)(qTh + (qt + 0) * 512 + lo8);
        qf[1] = *(const bf16x8*)(qTh + (qt + 1) * 512 + lo8);
    }

    f32x4 oacc[4];
    const f32x4 zero = {0.f, 0.f, 0.f, 0.f};
    #pragma unroll
    for (int dt = 0; dt < 4; dt++) oacc[dt] = zero;
    float m_run = -1e30f, l_run = 0.f;

    const float cscale = 0.125f * 1.44269504f;
    const int qlo = qs + 16 * w;
    const int q = qlo + ln;  // this lane's softmax q-row
    const int lo_b = (q - WIN) < 0 ? 0 : (q - WIN);
    const int hi_b = (q + WIN) > (L_SEQ - 1) ? (L_SEQ - 1) : (q + WIN);

    // prologue: kt = 0 into buf 0
    {
        if (w < 4) {
            int st = (qs >> 4) - 8 + w;
            st = st < 0 ? 0 : (st > 255 ? 255 : st);
            const size_t kb = ((size_t)bh * 256 + st) * 2 * 512 + lo8;
            gload16(kTh + kb,       &sKh[0][(w * 2 + 0) * 512]);
            gload16(kTh + kb + 512, &sKh[0][(w * 2 + 1) * 512]);
        } else {
            const int u = w - 4;
            int vw = (qs >> 6) - 2;
            vw = vw < 0 ? 0 : (vw > 63 ? 63 : vw);
            const size_t vb = (((size_t)bh * 64 + vw) * 4 + u) * 2 * 512 + lo8;
            gload16(vTh + vb,       &sV[0][(u * 2 + 0) * 512]);
            gload16(vTh + vb + 512, &sV[0][(u * 2 + 1) * 512]);
        }
    }

    for (int kt = 0; kt < 6; kt++) {
        const int ks = qs - 128 + kt * 64;

        __syncthreads();  // drains stage(kt); all waves done reading buf[(kt+1)&1]

        if (kt < 5) {
            const int nb = (kt + 1) & 1;
            if (w < 4) {
                int st = (qs >> 4) - 8 + (kt + 1) * 4 + w;
                st = st < 0 ? 0 : (st > 255 ? 255 : st);
                const size_t kb = ((size_t)bh * 256 + st) * 2 * 512 + lo8;
                gload16(kTh + kb,       &sKh[nb][(w * 2 + 0) * 512]);
                gload16(kTh + kb + 512, &sKh[nb][(w * 2 + 1) * 512]);
            } else {
                const int u = w - 4;
                int vw = (qs >> 6) - 2 + kt + 1;
                vw = vw < 0 ? 0 : (vw > 63 ? 63 : vw);
                const size_t vb = (((size_t)bh * 64 + vw) * 4 + u) * 2 * 512 + lo8;
                gload16(vTh + vb,       &sV[nb][(u * 2 + 0) * 512]);
                gload16(vTh + vb + 512, &sV[nb][(u * 2 + 1) * 512]);
            }
        }
        const int cb = kt & 1;

        // per-jt dead flags (wave-uniform)
        bool dead[4];
        #pragma unroll
        for (int jt = 0; jt < 4; jt++) {
            const int klo = ks + 16 * jt;
            dead[jt] = (klo > qlo + 15 + WIN) || (klo + 15 < qlo - WIN) ||
                       (klo >= L_SEQ) || (klo + 15 < 0);
        }
        const bool hdead0 = dead[0] && dead[1];
        const bool hdead1 = dead[2] && dead[3];
        const bool ktAlive = !(hdead0 && hdead1);

        if (ktAlive) {
            // S^T = K Q^T (swapped operands)
            f32x4 st4[4];
            __builtin_amdgcn_s_setprio(1);
            #pragma unroll
            for (int jt = 0; jt < 4; jt++) {
                f32x4 a = zero;
                if (!dead[jt]) {
                    #pragma unroll
                    for (int kk = 0; kk < 2; kk++) {
                        const bf16x8 kh = *(const bf16x8*)&sKh[cb][(jt * 2 + kk) * 512 + lo8];
                        a = __builtin_amdgcn_mfma_f32_16x16x32_bf16(kh, qf[kk], a, 0, 0, 0);
                    }
                }
                st4[jt] = a;
            }
            __builtin_amdgcn_s_setprio(0);

            // unmasked row max (raw S), then scale once
            float mkr = -INFINITY;
            #pragma unroll
            for (int jt = 0; jt < 4; jt++)
                if (!dead[jt])
                    #pragma unroll
                    for (int r = 0; r < 4; r++)
                        mkr = fmaxf(mkr, st4[jt][r]);
            mkr = fmaxf(mkr, __shfl_xor(mkr, 16));
            mkr = fmaxf(mkr, __shfl_xor(mkr, 32));

            const float mnew = fmaxf(m_run, mkr * cscale);
            const bool raised = mnew > m_run;
            const float alpha = exp2f(m_run - mnew);
            m_run = mnew;

            // p = exp2(fma(S, cscale, -mnew)), masked to 0
            float ps = 0.f;
            #pragma unroll
            for (int jt = 0; jt < 4; jt++) {
                if (!dead[jt]) {
                    #pragma unroll
                    for (int r = 0; r < 4; r++) {
                        const int kcol = ks + jt * 16 + quad * 4 + r;
                        const bool ok = (kcol >= lo_b) && (kcol <= hi_b) && (kcol != q);
                        float p = exp2f(st4[jt][r] * cscale - mnew);
                        p = ok ? p : 0.f;
                        st4[jt][r] = p;
                        ps += p;
                    }
                }
            }
            ps += __shfl_xor(ps, 16);
            ps += __shfl_xor(ps, 32);
            l_run = l_run * alpha + ps;

            // rescale O only if some lane raised its max
            if (__any(raised)) {
                float ar[4];
                #pragma unroll
                for (int r = 0; r < 4; r++)
                    ar[r] = __shfl(alpha, quad * 4 + r);
                #pragma unroll
                for (int dt = 0; dt < 4; dt++)
                    #pragma unroll
                    for (int r = 0; r < 4; r++)
                        oacc[dt][r] *= ar[r];
            }

            // P -> sP image (row = q&15 = ln, k = key-in-window), uint2 writes
            #pragma unroll
            for (int jt = 0; jt < 4; jt++) {
                const bool hd = (jt < 2) ? hdead0 : hdead1;
                if (!hd) {
                    uint2 pw;
                    if (!dead[jt]) {
                        pw.x = pk2bf(st4[jt][0], st4[jt][1]);
                        pw.y = pk2bf(st4[jt][2], st4[jt][3]);
                    } else { pw.x = 0u; pw.y = 0u; }
                    const int slot = ((jt & 1) * 2 + (quad >> 1)) * 16 + ln;
                    *(uint2*)&sP[w * 1024 + (jt >> 1) * 512 + slot * 8 + (quad & 1) * 4] = pw;
                }
            }

            // O += P V (original operand order; pf as A from image); skip dead halves
            #pragma unroll
            for (int kk = 0; kk < 2; kk++) {
                const bool hd = (kk == 0) ? hdead0 : hdead1;
                if (!hd) {
                    const bf16x8 pf = *(const bf16x8*)&sP[w * 1024 + kk * 512 + lo8];
                    __builtin_amdgcn_s_setprio(1);
                    #pragma unroll
                    for (int dt = 0; dt < 4; dt++) {
                        const bf16x8 vf = *(const bf16x8*)&sV[cb][(dt * 2 + kk) * 512 + lo8];
                        oacc[dt] = __builtin_amdgcn_mfma_f32_16x16x32_bf16(pf, vf, oacc[dt], 0, 0, 0);
                    }
                    __builtin_amdgcn_s_setprio(0);
                }
            }
        }
    }

    // epilogue: lane holds O[q=qlo+quad*4+r][d=dt*16+ln];
    // l for row quad*4+r is broadcast from lane (quad*4+r).
    const int Rt = ((b * L_SEQ + qs) >> 4) + w;
    float invl[4];
    #pragma unroll
    for (int r = 0; r < 4; r++) {
        const float lr = __shfl(l_run, quad * 4 + r);
        invl[r] = __builtin_amdgcn_rcpf(lr);
    }
    #pragma unroll
    for (int dt = 0; dt < 4; dt++) {
        const uint_t pa = pk2bf(oacc[dt][0] * invl[0], oacc[dt][1] * invl[1]);
        const uint_t pc = pk2bf(oacc[dt][2] * invl[2], oacc[dt][3] * invl[3]);
        const int tile = Rt * 16 + h * 2 + (dt >> 1);
        const int slot0 = ((dt & 1) * 2 + (ln >> 3)) * 16 + quad * 4;
        const size_t idx0 = (size_t)tile * 512 + slot0 * 8 + (ln & 7);
        outh[idx0]      = (ushort_t)pa;
        outh[idx0 + 8]  = (ushort_t)(pa >> 16);
        outh[idx0 + 16] = (ushort_t)pc;
        outh[idx0 + 24] = (ushort_t)(pc >> 16);
    }
}

// ---------- GEMM2: out projection, 128x64, BK=64, TRIPLE buffer, counted ----
__global__ __launch_bounds__(512) void gemm_out(
    const ushort_t* __restrict__ Ah,
    const ushort_t* __restrict__ Wh,
    const float* __restrict__ bias, float* __restrict__ C) {
    __shared__ __align__(16) ushort_t sAh[3][16 * 512];
    __shared__ __align__(16) ushort_t sWh[3][8 * 512];

    const int tid = threadIdx.x, lane = tid & 63, w = tid >> 6;
    const int wm = w & 3, wn = w >> 2, ln = lane & 15, quad = lane >> 4;
    const int bx = blockIdx.x, by = blockIdx.y;
    const int lo8 = lane * 8;
    const int wu = __builtin_amdgcn_readfirstlane(w);

    const ushort_t* sA0 = &sAh[0][0];
    const ushort_t* sW0 = &sWh[0][0];
    const int BUFA = 16 * 512, BUFW = 8 * 512;

    f32x4 acc[2][2];
    const f32x4 zero = {0.f, 0.f, 0.f, 0.f};
    #pragma unroll
    for (int i = 0; i < 2; i++)
        #pragma unroll
        for (int j = 0; j < 2; j++) acc[i][j] = zero;

    const ushort_t* pb[3];
    ushort_t* db[3];  // dst in buffer 0
    int ds[3];        // per-slot buffer stride
    #pragma unroll
    for (int t = 0; t < 3; t++) {
        const int g = wu * 3 + t;
        if (g < 16) {
            pb[t] = Ah + ((size_t)(bx * 8 + (g >> 1)) * 16 + (g & 1)) * 512;
            db[t] = &sAh[0][g * 512]; ds[t] = BUFA;
        } else {
            const int u = g - 16;
            pb[t] = Wh + ((size_t)(by * 4 + (u >> 1)) * 16 + (u & 1)) * 512;
            db[t] = &sWh[0][u * 512]; ds[t] = BUFW;
        }
    }

    // prologue: KT=0 -> buf0, KT=1 -> buf1 (FIFO order)
    #pragma unroll
    for (int t = 0; t < 3; t++) gload16(pb[t] + lo8, db[t]);
    #pragma unroll
    for (int t = 0; t < 3; t++) gload16(pb[t] + 1024 + lo8, db[t] + ds[t]);

    int bw = 2, br = 0;
    for (int KT = 0; KT < 8; KT++) {
        if (KT < 7) asm volatile("s_waitcnt vmcnt(3) lgkmcnt(0)" ::: "memory");
        else        asm volatile("s_waitcnt vmcnt(0) lgkmcnt(0)" ::: "memory");
        __builtin_amdgcn_s_barrier();
        __builtin_amdgcn_sched_barrier(0);

        if (KT < 6) {
            const int koff = (KT + 2) * 1024;
            #pragma unroll
            for (int t = 0; t < 3; t++)
                gload16(pb[t] + koff + lo8, db[t] + bw * ds[t]);
            bw = (bw == 2) ? 0 : bw + 1;
        }

        const int broA = br * BUFA, broW = br * BUFW;
        br = (br == 2) ? 0 : br + 1;

        #pragma unroll
        for (int ks = 0; ks < 2; ks++) {
            bf16x8 fah[2];
            #pragma unroll
            for (int i = 0; i < 2; i++)
                fah[i] = *(const bf16x8*)&sA0[broA + ((wm * 2 + i) * 2 + ks) * 512 + lo8];
            #pragma unroll
            for (int j = 0; j < 2; j++) {
                const bf16x8 fbh = *(const bf16x8*)&sW0[broW + ((wn * 2 + j) * 2 + ks) * 512 + lo8];
                #pragma unroll
                for (int i = 0; i < 2; i++)
                    acc[i][j] = __builtin_amdgcn_mfma_f32_16x16x32_bf16(fah[i], fbh, acc[i][j], 0, 0, 0);
            }
        }
    }

    #pragma unroll
    for (int i = 0; i < 2; i++) {
        const int row0 = bx * 128 + wm * 32 + i * 16 + quad * 4;
        #pragma unroll
        for (int j = 0; j < 2; j++) {
            const int col = by * 64 + wn * 32 + j * 16 + ln;
            const float bv = bias[col];
            #pragma unroll
            for (int r = 0; r < 4; r++)
                C[(size_t)(row0 + r) * E_DIM + col] = acc[i][j][r] + bv;
        }
    }
}

extern "C" void kernel_launch(void* const* d_in, const int* in_sizes, int n_in,
                              void* d_out, int out_size, void* d_ws, size_t ws_size,
                              hipStream_t stream) {
    const float* x         = (const float*)d_in[0];
    const float* in_proj_w = (const float*)d_in[1];
    const float* in_proj_b = (const float*)d_in[2];
    const float* out_w     = (const float*)d_in[3];
    const float* out_b     = (const float*)d_in[4];
    float* out = (float*)d_out;

    const int N = B_SZ * L_SEQ;  // 8192
    const size_t NE = (size_t)N * E_DIM;  // 4.19M elems

    char* p = (char*)d_ws;
    ushort_t* xh  = (ushort_t*)p; p += NE * 2;
    ushort_t* w1h = (ushort_t*)p; p += (size_t)3 * E_DIM * E_DIM * 2;
    ushort_t* w2h = (ushort_t*)p; p += (size_t)E_DIM * E_DIM * 2;
    ushort_t* qTh = (ushort_t*)p; p += NE * 2;
    ushort_t* kTh = (ushort_t*)p; p += NE * 2;
    ushort_t* vTh = (ushort_t*)p; p += NE * 2;
    ushort_t* ath = (ushort_t*)p; p += NE * 2;
    // total ~46 MB

    convertX<<<2560, 256, 0, stream>>>(x, xh, in_proj_w, w1h, out_w, w2h);

    gemm_qkv<<<dim3(64, 12), 256, 0, stream>>>(
        xh, w1h, in_proj_b, qTh, kTh, vTh);

    attn_mfma<<<dim3(L_SEQ / 128, H_DIM, B_SZ), 512, 0, stream>>>(
        qTh, kTh, vTh, ath);

    gemm_out<<<dim3(64, 8), 512, 0, stream>>>(
        ath, w2h, out_b, out);
}

// Round 5
// 126.615 us; speedup vs baseline: 1.0314x; 1.0036x over previous
//
#include <hip/hip_runtime.h>
#include <math.h>

#define E_DIM 512
#define H_DIM 8
#define WIN 128
#define L_SEQ 4096
#define B_SZ 2

typedef unsigned short ushort_t;
typedef unsigned int uint_t;
typedef __attribute__((ext_vector_type(8))) __bf16 bf16x8;
typedef __attribute__((ext_vector_type(4))) float f32x4;

// ---------- bf16 helpers ----------
__device__ __forceinline__ ushort_t f2bf(float f) {
    uint_t u = __float_as_uint(f);
    u = u + 0x7fffu + ((u >> 16) & 1u);
    return (ushort_t)(u >> 16);
}
// packed f32x2 -> bf16x2 (RNE), single instruction
__device__ __forceinline__ uint_t pk2bf(float lo, float hi) {
    uint_t r;
    asm("v_cvt_pk_bf16_f32 %0, %1, %2" : "=v"(r) : "v"(lo), "v"(hi));
    return r;
}

__device__ __forceinline__ void gload16(const ushort_t* g, ushort_t* l) {
    __builtin_amdgcn_global_load_lds(
        (const __attribute__((address_space(1))) void*)g,
        (__attribute__((address_space(3))) void*)l,
        16, 0, 0);
}

// ===== Tile image (16 rows x 32 k = 512 elems = 1 KB) =====
// idx = slot*8 + (k&7), slot = ((k>>3)&3)*16 + (row&15)  [slot = quad*16+ln]
// A-frag & B-frag both read at lane*8 within a tile image.

// ---------- convert: x, w1, w2 -> hi-only tiled bf16 ----------
__global__ __launch_bounds__(256) void convertX(
    const float* __restrict__ x,  ushort_t* __restrict__ xh,
    const float* __restrict__ w1, ushort_t* __restrict__ w1h,
    const float* __restrict__ w2, ushort_t* __restrict__ w2h) {
    int sg = blockIdx.x * 256 + threadIdx.x;
    const float* src; ushort_t* dh;
    if (sg < 524288)      { src = x;  dh = xh; }
    else if (sg < 622592) { src = w1; dh = w1h; sg -= 524288; }
    else                  { src = w2; dh = w2h; sg -= 622592; }
    const int tile = sg >> 6, slot = sg & 63;
    const int row = (tile >> 4) * 16 + (slot & 15);
    const int k   = (tile & 15) * 32 + (slot >> 4) * 8;
    const float4 v0 = *(const float4*)&src[(size_t)row * 512 + k];
    const float4 v1 = *(const float4*)&src[(size_t)row * 512 + k + 4];
    uint4 ov;
    ov.x = pk2bf(v0.x, v0.y);
    ov.y = pk2bf(v0.z, v0.w);
    ov.z = pk2bf(v1.x, v1.y);
    ov.w = pk2bf(v1.z, v1.w);
    *(uint4*)(dh + (size_t)sg * 8) = ov;
}

// ---------- GEMM1: qkv projection, BK=32, TRIPLE buffer, counted vmcnt ----
// 128x128 tile, grid (64, 12). by<4: q, [4,8): k, >=8: v. All outputs hi-only.
// Per iter: wait own loads(kt) (vmcnt<=4 keeps loads(kt+1) in flight),
// lgkmcnt(0) (my prev-buffer ds_reads done), s_barrier, stage(kt+2), compute.
__global__ __launch_bounds__(256) void gemm_qkv(
    const ushort_t* __restrict__ Ah,
    const ushort_t* __restrict__ Wh,
    const float* __restrict__ bias,
    ushort_t* __restrict__ qTh,
    ushort_t* __restrict__ kTh,
    ushort_t* __restrict__ vTh) {
    __shared__ __align__(16) ushort_t sAh[3][8 * 512];
    __shared__ __align__(16) ushort_t sWh[3][8 * 512];

    const int tid = threadIdx.x, lane = tid & 63, w = tid >> 6;
    const int wm = w & 1, wn = w >> 1, ln = lane & 15, quad = lane >> 4;
    const int bx = blockIdx.x, by = blockIdx.y;
    const int lo8 = lane * 8;
    const int wu = __builtin_amdgcn_readfirstlane(w);

    const ushort_t* sA0 = &sAh[0][0];
    const ushort_t* sW0 = &sWh[0][0];
    const int BUF = 8 * 512;  // elems per buffer (both arrays)

    f32x4 acc[4][4];
    const f32x4 zero = {0.f, 0.f, 0.f, 0.f};
    #pragma unroll
    for (int i = 0; i < 4; i++)
        #pragma unroll
        for (int j = 0; j < 4; j++) acc[i][j] = zero;

    // staging: 16 images per k-group (A 8, Wh 8), 4 per wave
    const ushort_t* pb[4];
    ushort_t* db[4];  // dst in buffer 0
    #pragma unroll
    for (int t = 0; t < 4; t++) {
        const int g = wu * 4 + t;
        if (g < 8) {
            pb[t] = Ah + ((size_t)(bx * 8 + g) * 16) * 512;
            db[t] = &sAh[0][g * 512];
        } else {
            const int u = g - 8;
            pb[t] = Wh + ((size_t)(by * 8 + u) * 16) * 512;
            db[t] = &sWh[0][u * 512];
        }
    }

    // prologue: stage kt=0 -> buf0, kt=1 -> buf1 (8 loads in FIFO order)
    #pragma unroll
    for (int t = 0; t < 4; t++) gload16(pb[t] + lo8, db[t]);
    #pragma unroll
    for (int t = 0; t < 4; t++) gload16(pb[t] + 512 + lo8, db[t] + BUF);

    int bw = 2, br = 0;
    for (int kt = 0; kt < 16; kt++) {
        if (kt < 15) asm volatile("s_waitcnt vmcnt(4) lgkmcnt(0)" ::: "memory");
        else         asm volatile("s_waitcnt vmcnt(0) lgkmcnt(0)" ::: "memory");
        __builtin_amdgcn_s_barrier();
        __builtin_amdgcn_sched_barrier(0);

        if (kt < 14) {
            const int koff = (kt + 2) * 512;
            const int bwo = bw * BUF;
            #pragma unroll
            for (int t = 0; t < 4; t++)
                gload16(pb[t] + koff + lo8, db[t] + bwo);
            bw = (bw == 2) ? 0 : bw + 1;
        }

        const int bro = br * BUF;
        br = (br == 2) ? 0 : br + 1;

        bf16x8 fah[4];
        #pragma unroll
        for (int i = 0; i < 4; i++)
            fah[i] = *(const bf16x8*)&sA0[bro + (wm * 4 + i) * 512 + lo8];
        #pragma unroll
        for (int j = 0; j < 4; j++) {
            const bf16x8 fbh = *(const bf16x8*)&sW0[bro + (wn * 4 + j) * 512 + lo8];
            #pragma unroll
            for (int i = 0; i < 4; i++)
                acc[i][j] = __builtin_amdgcn_mfma_f32_16x16x32_bf16(fah[i], fbh, acc[i][j], 0, 0, 0);
        }
    }

    // ---- epilogue: C/D layout col=ln (within j-tile), row=quad*4+r ----
    const int b = bx >> 5;
    const int h = 2 * (by & 3) + wn;
    if (by < 8) {
        ushort_t* dh = (by < 4) ? qTh : kTh;
        #pragma unroll
        for (int i = 0; i < 4; i++) {
            const int rt = (bx & 31) * 8 + wm * 4 + i;
            const size_t tb = ((size_t)(b * 8 + h) * 256 + rt) * 2;
            #pragma unroll
            for (int j = 0; j < 4; j++) {
                const float bv = bias[by * 128 + wn * 64 + j * 16 + ln];
                const size_t tile = tb + (j >> 1);
                const uint_t pa = pk2bf(acc[i][j][0] + bv, acc[i][j][1] + bv);
                const uint_t pc = pk2bf(acc[i][j][2] + bv, acc[i][j][3] + bv);
                const int slot0 = ((j * 2 + (ln >> 3)) & 3) * 16 + quad * 4;
                const size_t idx0 = tile * 512 + slot0 * 8 + (ln & 7);
                dh[idx0]      = (ushort_t)pa;
                dh[idx0 + 8]  = (ushort_t)(pa >> 16);
                dh[idx0 + 16] = (ushort_t)pc;
                dh[idx0 + 24] = (ushort_t)(pc >> 16);
            }
        }
    } else {
        const int kwin = (bx & 31) * 2 + wm;
        #pragma unroll
        for (int i = 0; i < 4; i++) {
            const int kk = i >> 1;
            #pragma unroll
            for (int j = 0; j < 4; j++) {
                const float bv = bias[by * 128 + wn * 64 + j * 16 + ln];
                const size_t tile = (((size_t)(b * 8 + h) * 64 + kwin) * 4 + j) * 2 + kk;
                // klq = quad*4+r: klq>>3 == quad>>1 (r-invariant) -> 4 consecutive elems
                const uint_t pa = pk2bf(acc[i][j][0] + bv, acc[i][j][1] + bv);
                const uint_t pc = pk2bf(acc[i][j][2] + bv, acc[i][j][3] + bv);
                const int slot = ((i & 1) * 2 + (quad >> 1)) * 16 + ln;
                uint2 ov; ov.x = pa; ov.y = pc;
                *(uint2*)&vTh[tile * 512 + slot * 8 + (quad & 1) * 4] = ov;
            }
        }
    }
}

// ---------- attention: 128-q blocks, 8 waves, swapped QK^T, scalar softmax --
// S^T = mfma(K,Q): lane (ln,quad) holds S[q=qlo+ln][k=ks+jt*16+quad*4+r].
// Deferred-max online softmax: shared per-row m (any m >= rowmax-8 is valid;
// p <= 2^8). Trigger check is shuffle-free; cross-quad max reduce + O/l
// rescale only on trigger. l is a per-lane partial, reduced ONCE in epilogue.
// K/V triple-buffered with counted vmcnt (loads for kt+1/kt+2 stay in flight).
__global__ __launch_bounds__(512) void attn_mfma(
    const ushort_t* __restrict__ qTh,
    const ushort_t* __restrict__ kTh,
    const ushort_t* __restrict__ vTh,
    ushort_t* __restrict__ outh) {
    __shared__ __align__(16) ushort_t sKh[3][8 * 512];
    __shared__ __align__(16) ushort_t sV [3][8 * 512];
    __shared__ __align__(16) ushort_t sP [16 * 512];

    const int qs = blockIdx.x * 128;
    const int h = blockIdx.y, b = blockIdx.z;
    const int bh = b * 8 + h;
    const int tid = threadIdx.x, lane = tid & 63;
    const int w = tid >> 6, ln = lane & 15, quad = lane >> 4;
    const int lo8 = lane * 8;

    // Q fragments (hi only)
    bf16x8 qf[2];
    {
        const size_t qt = ((size_t)bh * 256 + (qs >> 4) + w) * 2;
        qf[0] = *(const bf16x8*)(qTh + (qt + 0) * 512 + lo8);
        qf[1] = *(const bf16x8*)(qTh + (qt + 1) * 512 + lo8);
    }

    f32x4 oacc[4];
    const f32x4 zero = {0.f, 0.f, 0.f, 0.f};
    #pragma unroll
    for (int dt = 0; dt < 4; dt++) oacc[dt] = zero;
    float m_run = -1e30f, l_loc = 0.f;

    const float cscale = 0.125f * 1.44269504f;
    const int qlo = qs + 16 * w;
    const int q = qlo + ln;  // this lane's softmax q-row
    const int lo_b = (q - WIN) < 0 ? 0 : (q - WIN);
    const int hi_b = (q + WIN) > (L_SEQ - 1) ? (L_SEQ - 1) : (q + WIN);

    // stage K/V for k-tile t into buffer bi (2 gload16 per wave)
    auto stage = [&](int t, int bi) {
        if (w < 4) {
            int st = (qs >> 4) - 8 + t * 4 + w;
            st = st < 0 ? 0 : (st > 255 ? 255 : st);
            const size_t kb = ((size_t)bh * 256 + st) * 2 * 512 + lo8;
            gload16(kTh + kb,       &sKh[bi][(w * 2 + 0) * 512]);
            gload16(kTh + kb + 512, &sKh[bi][(w * 2 + 1) * 512]);
        } else {
            const int u = w - 4;
            int vw = (qs >> 6) - 2 + t;
            vw = vw < 0 ? 0 : (vw > 63 ? 63 : vw);
            const size_t vb = (((size_t)bh * 64 + vw) * 4 + u) * 2 * 512 + lo8;
            gload16(vTh + vb,       &sV[bi][(u * 2 + 0) * 512]);
            gload16(vTh + vb + 512, &sV[bi][(u * 2 + 1) * 512]);
        }
    };

    // prologue: kt0 -> buf0, kt1 -> buf1 (4 loads in flight per wave)
    stage(0, 0);
    stage(1, 1);

    #pragma unroll
    for (int kt = 0; kt < 6; kt++) {
        const int ks = qs - 128 + kt * 64;

        // own loads for kt landed (oldest 2); kt+1's 2 stay in flight
        if (kt < 5) asm volatile("s_waitcnt vmcnt(2) lgkmcnt(0)" ::: "memory");
        else        asm volatile("s_waitcnt vmcnt(0) lgkmcnt(0)" ::: "memory");
        __builtin_amdgcn_s_barrier();
        __builtin_amdgcn_sched_barrier(0);

        // stage kt+2 into buf[(kt+2)%3] (= buffer read at kt-1, all done)
        if (kt < 4) stage(kt + 2, (kt + 2) % 3);
        const int cb = kt % 3;

        // per-jt dead flags (wave-uniform)
        bool dead[4];
        #pragma unroll
        for (int jt = 0; jt < 4; jt++) {
            const int klo = ks + 16 * jt;
            dead[jt] = (klo > qlo + 15 + WIN) || (klo + 15 < qlo - WIN) ||
                       (klo >= L_SEQ) || (klo + 15 < 0);
        }
        const bool hdead0 = dead[0] && dead[1];
        const bool hdead1 = dead[2] && dead[3];
        const bool ktAlive = !(hdead0 && hdead1);

        if (ktAlive) {
            // S^T = K Q^T (swapped operands)
            f32x4 st4[4];
            __builtin_amdgcn_s_setprio(1);
            #pragma unroll
            for (int jt = 0; jt < 4; jt++) {
                f32x4 a = zero;
                if (!dead[jt]) {
                    #pragma unroll
                    for (int kk = 0; kk < 2; kk++) {
                        const bf16x8 kh = *(const bf16x8*)&sKh[cb][(jt * 2 + kk) * 512 + lo8];
                        a = __builtin_amdgcn_mfma_f32_16x16x32_bf16(kh, qf[kk], a, 0, 0, 0);
                    }
                }
                st4[jt] = a;
            }
            __builtin_amdgcn_s_setprio(0);

            // per-lane local max over unmasked superset (raw S)
            float lmax = -INFINITY;
            #pragma unroll
            for (int jt = 0; jt < 4; jt++)
                if (!dead[jt])
                    #pragma unroll
                    for (int r = 0; r < 4; r++)
                        lmax = fmaxf(lmax, st4[jt][r]);

            // deferred-max: only reduce + rescale when some row grows past THR=8
            const bool trig = __any(lmax * cscale > m_run + 8.f);
            if (trig) {
                float mk = fmaxf(lmax, __shfl_xor(lmax, 16));
                mk = fmaxf(mk, __shfl_xor(mk, 32));
                const float mnew = fmaxf(m_run, mk * cscale);
                const float alpha = exp2f(m_run - mnew);
                m_run = mnew;
                l_loc *= alpha;
                float ar[4];
                #pragma unroll
                for (int r = 0; r < 4; r++)
                    ar[r] = __shfl(alpha, quad * 4 + r);
                #pragma unroll
                for (int dt = 0; dt < 4; dt++)
                    #pragma unroll
                    for (int r = 0; r < 4; r++)
                        oacc[dt][r] *= ar[r];
            }

            // p = exp2(S*cscale - m), masked to 0; accumulate per-lane l
            #pragma unroll
            for (int jt = 0; jt < 4; jt++) {
                if (!dead[jt]) {
                    #pragma unroll
                    for (int r = 0; r < 4; r++) {
                        const int kcol = ks + jt * 16 + quad * 4 + r;
                        const bool ok = (kcol >= lo_b) && (kcol <= hi_b) && (kcol != q);
                        float p = exp2f(st4[jt][r] * cscale - m_run);
                        p = ok ? p : 0.f;
                        st4[jt][r] = p;
                        l_loc += p;
                    }
                }
            }

            // P -> sP image (row = q&15 = ln, k = key-in-window), uint2 writes
            #pragma unroll
            for (int jt = 0; jt < 4; jt++) {
                const bool hd = (jt < 2) ? hdead0 : hdead1;
                if (!hd) {
                    uint2 pw;
                    if (!dead[jt]) {
                        pw.x = pk2bf(st4[jt][0], st4[jt][1]);
                        pw.y = pk2bf(st4[jt][2], st4[jt][3]);
                    } else { pw.x = 0u; pw.y = 0u; }
                    const int slot = ((jt & 1) * 2 + (quad >> 1)) * 16 + ln;
                    *(uint2*)&sP[w * 1024 + (jt >> 1) * 512 + slot * 8 + (quad & 1) * 4] = pw;
                }
            }

            // O += P V (pf as A from image); skip dead halves
            #pragma unroll
            for (int kk = 0; kk < 2; kk++) {
                const bool hd = (kk == 0) ? hdead0 : hdead1;
                if (!hd) {
                    const bf16x8 pf = *(const bf16x8*)&sP[w * 1024 + kk * 512 + lo8];
                    __builtin_amdgcn_s_setprio(1);
                    #pragma unroll
                    for (int dt = 0; dt < 4; dt++) {
                        const bf16x8 vf = *(const bf16x8*)&sV[cb][(dt * 2 + kk) * 512 + lo8];
                        oacc[dt] = __builtin_amdgcn_mfma_f32_16x16x32_bf16(pf, vf, oacc[dt], 0, 0, 0);
                    }
                    __builtin_amdgcn_s_setprio(0);
                }
            }
        }
    }

    // epilogue: single cross-quad l reduce, then lane holds
    // O[q=qlo+quad*4+r][d=dt*16+ln]; l for row quad*4+r broadcast from lane.
    float ls = l_loc;
    ls += __shfl_xor(ls, 16);
    ls += __shfl_xor(ls, 32);
    const int Rt = ((b * L_SEQ + qs) >> 4) + w;
    float invl[4];
    #pragma unroll
    for (int r = 0; r < 4; r++) {
        const float lr = __shfl(ls, quad * 4 + r);
        invl[r] = __builtin_amdgcn_rcpf(lr);
    }
    #pragma unroll
    for (int dt = 0; dt < 4; dt++) {
        const uint_t pa = pk2bf(oacc[dt][0] * invl[0], oacc[dt][1] * invl[1]);
        const uint_t pc = pk2bf(oacc[dt][2] * invl[2], oacc[dt][3] * invl[3]);
        const int tile = Rt * 16 + h * 2 + (dt >> 1);
        const int slot0 = ((dt & 1) * 2 + (ln >> 3)) * 16 + quad * 4;
        const size_t idx0 = (size_t)tile * 512 + slot0 * 8 + (ln & 7);
        outh[idx0]      = (ushort_t)pa;
        outh[idx0 + 8]  = (ushort_t)(pa >> 16);
        outh[idx0 + 16] = (ushort_t)pc;
        outh[idx0 + 24] = (ushort_t)(pc >> 16);
    }
}

// ---------- GEMM2: out projection, 128x64, BK=64, TRIPLE buffer, counted ----
__global__ __launch_bounds__(512) void gemm_out(
    const ushort_t* __restrict__ Ah,
    const ushort_t* __restrict__ Wh,
    const float* __restrict__ bias, float* __restrict__ C) {
    __shared__ __align__(16) ushort_t sAh[3][16 * 512];
    __shared__ __align__(16) ushort_t sWh[3][8 * 512];

    const int tid = threadIdx.x, lane = tid & 63, w = tid >> 6;
    const int wm = w & 3, wn = w >> 2, ln = lane & 15, quad = lane >> 4;
    const int bx = blockIdx.x, by = blockIdx.y;
    const int lo8 = lane * 8;
    const int wu = __builtin_amdgcn_readfirstlane(w);

    const ushort_t* sA0 = &sAh[0][0];
    const ushort_t* sW0 = &sWh[0][0];
    const int BUFA = 16 * 512, BUFW = 8 * 512;

    f32x4 acc[2][2];
    const f32x4 zero = {0.f, 0.f, 0.f, 0.f};
    #pragma unroll
    for (int i = 0; i < 2; i++)
        #pragma unroll
        for (int j = 0; j < 2; j++) acc[i][j] = zero;

    const ushort_t* pb[3];
    ushort_t* db[3];  // dst in buffer 0
    int ds[3];        // per-slot buffer stride
    #pragma unroll
    for (int t = 0; t < 3; t++) {
        const int g = wu * 3 + t;
        if (g < 16) {
            pb[t] = Ah + ((size_t)(bx * 8 + (g >> 1)) * 16 + (g & 1)) * 512;
            db[t] = &sAh[0][g * 512]; ds[t] = BUFA;
        } else {
            const int u = g - 16;
            pb[t] = Wh + ((size_t)(by * 4 + (u >> 1)) * 16 + (u & 1)) * 512;
            db[t] = &sWh[0][u * 512]; ds[t] = BUFW;
        }
    }

    // prologue: KT=0 -> buf0, KT=1 -> buf1 (FIFO order)
    #pragma unroll
    for (int t = 0; t < 3; t++) gload16(pb[t] + lo8, db[t]);
    #pragma unroll
    for (int t = 0; t < 3; t++) gload16(pb[t] + 1024 + lo8, db[t] + ds[t]);

    int bw = 2, br = 0;
    for (int KT = 0; KT < 8; KT++) {
        if (KT < 7) asm volatile("s_waitcnt vmcnt(3) lgkmcnt(0)" ::: "memory");
        else        asm volatile("s_waitcnt vmcnt(0) lgkmcnt(0)" ::: "memory");
        __builtin_amdgcn_s_barrier();
        __builtin_amdgcn_sched_barrier(0);

        if (KT < 6) {
            const int koff = (KT + 2) * 1024;
            #pragma unroll
            for (int t = 0; t < 3; t++)
                gload16(pb[t] + koff + lo8, db[t] + bw * ds[t]);
            bw = (bw == 2) ? 0 : bw + 1;
        }

        const int broA = br * BUFA, broW = br * BUFW;
        br = (br == 2) ? 0 : br + 1;

        #pragma unroll
        for (int ks = 0; ks < 2; ks++) {
            bf16x8 fah[2];
            #pragma unroll
            for (int i = 0; i < 2; i++)
                fah[i] = *(const bf16x8*)&sA0[broA + ((wm * 2 + i) * 2 + ks) * 512 + lo8];
            #pragma unroll
            for (int j = 0; j < 2; j++) {
                const bf16x8 fbh = *(const bf16x8*)&sW0[broW + ((wn * 2 + j) * 2 + ks) * 512 + lo8];
                #pragma unroll
                for (int i = 0; i < 2; i++)
                    acc[i][j] = __builtin_amdgcn_mfma_f32_16x16x32_bf16(fah[i], fbh, acc[i][j], 0, 0, 0);
            }
        }
    }

    #pragma unroll
    for (int i = 0; i < 2; i++) {
        const int row0 = bx * 128 + wm * 32 + i * 16 + quad * 4;
        #pragma unroll
        for (int j = 0; j < 2; j++) {
            const int col = by * 64 + wn * 32 + j * 16 + ln;
            const float bv = bias[col];
            #pragma unroll
            for (int r = 0; r < 4; r++)
                C[(size_t)(row0 + r) * E_DIM + col] = acc[i][j][r] + bv;
        }
    }
}

extern "C" void kernel_launch(void* const* d_in, const int* in_sizes, int n_in,
                              void* d_out, int out_size, void* d_ws, size_t ws_size,
                              hipStream_t stream) {
    const float* x         = (const float*)d_in[0];
    const float* in_proj_w = (const float*)d_in[1];
    const float* in_proj_b = (const float*)d_in[2];
    const float* out_w     = (const float*)d_in[3];
    const float* out_b     = (const float*)d_in[4];
    float* out = (float*)d_out;

    const int N = B_SZ * L_SEQ;  // 8192
    const size_t NE = (size_t)N * E_DIM;  // 4.19M elems

    char* p = (char*)d_ws;
    ushort_t* xh  = (ushort_t*)p; p += NE * 2;
    ushort_t* w1h = (ushort_t*)p; p += (size_t)3 * E_DIM * E_DIM * 2;
    ushort_t* w2h = (ushort_t*)p; p += (size_t)E_DIM * E_DIM * 2;
    ushort_t* qTh = (ushort_t*)p; p += NE * 2;
    ushort_t* kTh = (ushort_t*)p; p += NE * 2;
    ushort_t* vTh = (ushort_t*)p; p += NE * 2;
    ushort_t* ath = (ushort_t*)p; p += NE * 2;
    // total ~46 MB

    convertX<<<2560, 256, 0, stream>>>(x, xh, in_proj_w, w1h, out_w, w2h);

    gemm_qkv<<<dim3(64, 12), 256, 0, stream>>>(
        xh, w1h, in_proj_b, qTh, kTh, vTh);

    attn_mfma<<<dim3(L_SEQ / 128, H_DIM, B_SZ), 512, 0, stream>>>(
        qTh, kTh, vTh, ath);

    gemm_out<<<dim3(64, 8), 512, 0, stream>>>(
        ath, w2h, out_b, out);
}